// Round 7
// baseline (741.592 us; speedup 1.0000x reference)
//
#include <hip/hip_runtime.h>
#include <math.h>

// ---------------------------------------------------------------------------
// VQ-VAE forward: NHWC bf16 trunk, MFMA convs, fused res blocks, fused
// enc_adj+VQ, MFMA im2col conv1, MFMA tc2, single merged prep dispatch.
// R2: XCD swizzle + FRELU fold. [442 us baseline]
// R3/R4/R5/R6 (REVERTED) triangulated the limiter:
//   - R6 halo (B global, ZERO prefetch): MfmaUtil 9 / VALU 7 / HBM 4% ->
//     exposed-global-B latency kills; staged-bytes cut didn't help.
//   - Cycle model of R2: LDS ~36KB/block/K-step (B-frag reads = 16KB,
//     redundant across 4 waves) at ~85B/cy/CU -> 430cy/step -> 26us conv3,
//     MfmaUtil ~12% -- MATCHES measurements. R2 is LDS-throughput bound,
//     dominated by the B path.
// R7: R2 structure exactly, but B never touches LDS: B-frags loaded
//     global->register with ONE-ITERATION prefetch (BP/BQ named sets,
//     x2-unrolled K-loop -- R5's proven-safe mechanism). Weights are
//     L1/L2-hot; LDS traffic 36->16KB per block-step (2.25x).
//     Applied to mfma_conv_k, res_fused loop1, tc2 B-read.
//
// Workspace layout (bytes):
//   [0 .. ~2.1MB)   transformed weights + counts/sse + Ebf + enorm1 + wc1b
//   H1  = 2097152   (64,64,64,64)  NHWC bf16  33.5MB   h1, later tc1 out
//   TR  = 35651584  (64,32,32,128) NHWC bf16  16.8MB   trunk ping
//   H3  = 52428800  (64,32,32,128) NHWC bf16  16.8MB   trunk pong
//   ZQ  = 85983232  (64,32,32,64)  NHWC bf16   8.4MB
//   IDX = 94371840  65536 u16      128KB
// ---------------------------------------------------------------------------

typedef unsigned short u16;
typedef __attribute__((ext_vector_type(8))) short bf16x8;
typedef __attribute__((ext_vector_type(4))) float f32x4;

__device__ __forceinline__ float bf2f(u16 h) {
    union { unsigned u; float f; } v; v.u = ((unsigned)h) << 16; return v.f;
}
__device__ __forceinline__ u16 f2bf(float f) {
    union { float f; unsigned u; } v; v.f = f;
    unsigned r = v.u + 0x7FFFu + ((v.u >> 16) & 1u);
    return (u16)(r >> 16);
}
__device__ __forceinline__ unsigned relu2(unsigned x) {
    return x & ~(((x & 0x80008000u) >> 15) * 0xFFFFu);
}
// XCD-aware bijective swizzle for gridX=512 (512 = 8 XCDs * 64 chunks).
__device__ __forceinline__ int swz512(int x) {
    return ((x & 7) << 6) | (x >> 3);
}

// ---------------- unified implicit-GEMM MFMA conv ----------------
// R7: TM=2, TN=4, 128-pixel blocks, COUT/64 col split. A staged via LDS
// (R2 path, depth-1 reg prefetch); B global->register, one-iteration
// prefetch via BP/BQ named sets in a x2-unrolled K-loop.
// TAPMODE: 0=1x1, 1=3x3, 2=4x4 stride2, 3=PAR4 transpose-conv parity.
template<int CIN, int COUT, int TAPMODE, bool RELU_IN, bool RELU_OUT,
         bool HAS_BIAS, bool RESID>
__global__ __launch_bounds__(256)
void mfma_conv_k(const u16* __restrict__ in, const u16* __restrict__ wT,
                 const float* __restrict__ bias, u16* __restrict__ out,
                 int Hin, int Win, int Hout, int Wout, int OS)
{
    constexpr int TM = 2;
    constexpr int LDA = 40;
    constexpr int NCH = CIN / 32;
    constexpr int NTAPS = (TAPMODE == 0) ? 1 : (TAPMODE == 1) ? 9
                        : (TAPMODE == 2) ? 16 : 4;
    constexpr int S = (TAPMODE == 2) ? 2 : 1;
    constexpr int TOTAL_IT = NTAPS * NCH;
    static_assert((TOTAL_IT & 1) == 0, "x2-unrolled K-loop needs even count");

    __shared__ alignas(16) u16 aT[128 * LDA];   // 10.2KB (bT removed)

    const int tid = threadIdx.x;
    const int m0 = swz512(blockIdx.x) * 128;
    const int colbase = blockIdx.y << 6;
    const int pz = (TAPMODE == 3) ? blockIdx.z : 0;
    const u16* wTb = (TAPMODE == 3) ? wT + (size_t)pz * 4 * COUT * CIN : wT;
    const int oph = (TAPMODE == 3) ? (pz >> 1) : 0;
    const int opw = (TAPMODE == 3) ? (pz & 1) : 0;
    const int n_img = m0 >> 10;
    const int pixbase = m0 & 1023;

    const int r = tid >> 1, half = tid & 1;
    const int pr = pixbase + r;
    const int ohr = pr >> 5, owr = pr & 31;
    const u16* inb = in + (size_t)n_img * Hin * Win * CIN;

    const int wv = tid >> 6, lane = tid & 63;
    const int q = lane >> 4, l16 = lane & 15;
    const int mbase = wv * 32;

    f32x4 acc[TM][4] = {};

    uint4 pa0, pa1;
    bf16x8 BP0, BP1, BP2, BP3, BQ0, BQ1, BQ2, BQ3;

#define LOAD_A(IT) do {                                                         \
        int t_ = (IT) / NCH, cc_ = ((IT) % NCH) * 32;                           \
        int dh_, dw_;                                                           \
        if (TAPMODE == 0)      { dh_ = 0;              dw_ = 0; }               \
        else if (TAPMODE == 1) { dh_ = t_/3 - 1;       dw_ = t_%3 - 1; }        \
        else if (TAPMODE == 2) { dh_ = (t_>>2) - 1;    dw_ = (t_&3) - 1; }      \
        else                   { dh_ = (pz>>1) - (t_>>1); dw_ = (pz&1) - (t_&1); } \
        int ih_ = ohr * S + dh_;                                                \
        int iw_ = owr * S + dw_;                                                \
        bool ok_ = ((unsigned)ih_ < (unsigned)Hin) &&                           \
                   ((unsigned)iw_ < (unsigned)Win);                             \
        pa0 = (uint4){0,0,0,0}; pa1 = (uint4){0,0,0,0};                         \
        if (ok_) {                                                              \
            const u16* as_ = inb + ((size_t)ih_ * Win + iw_) * CIN              \
                             + half * 16 + cc_;                                 \
            pa0 = *(const uint4*)(as_);                                         \
            pa1 = *(const uint4*)(as_ + 8);                                     \
        }                                                                       \
    } while (0)

#define LOADB(IT, B0, B1, B2, B3) do {                                          \
        int t_ = (IT) / NCH, cc_ = ((IT) % NCH) * 32;                           \
        const u16* wb_ = wTb + ((size_t)t_ * COUT + colbase + l16) * CIN        \
                         + cc_ + q * 8;                                         \
        B0 = *(const bf16x8*)(wb_);                                             \
        B1 = *(const bf16x8*)(wb_ + (size_t)16 * CIN);                          \
        B2 = *(const bf16x8*)(wb_ + (size_t)32 * CIN);                          \
        B3 = *(const bf16x8*)(wb_ + (size_t)48 * CIN);                          \
    } while (0)

#define STAGE_A() do {                                                          \
        uint4 a0 = pa0, a1 = pa1;                                               \
        if (RELU_IN) {                                                          \
            a0.x = relu2(a0.x); a0.y = relu2(a0.y);                             \
            a0.z = relu2(a0.z); a0.w = relu2(a0.w);                             \
            a1.x = relu2(a1.x); a1.y = relu2(a1.y);                             \
            a1.z = relu2(a1.z); a1.w = relu2(a1.w);                             \
        }                                                                       \
        *(uint4*)&aT[r * LDA + half * 16]     = a0;                             \
        *(uint4*)&aT[r * LDA + half * 16 + 8] = a1;                             \
    } while (0)

#define DO_MFMA(B0, B1, B2, B3) do {                                            \
        bf16x8 af0 = *(const bf16x8*)&aT[(mbase + l16) * LDA + q * 8];          \
        bf16x8 af1 = *(const bf16x8*)&aT[(mbase + 16 + l16) * LDA + q * 8];     \
        acc[0][0] = __builtin_amdgcn_mfma_f32_16x16x32_bf16(af0, B0, acc[0][0], 0, 0, 0); \
        acc[0][1] = __builtin_amdgcn_mfma_f32_16x16x32_bf16(af0, B1, acc[0][1], 0, 0, 0); \
        acc[0][2] = __builtin_amdgcn_mfma_f32_16x16x32_bf16(af0, B2, acc[0][2], 0, 0, 0); \
        acc[0][3] = __builtin_amdgcn_mfma_f32_16x16x32_bf16(af0, B3, acc[0][3], 0, 0, 0); \
        acc[1][0] = __builtin_amdgcn_mfma_f32_16x16x32_bf16(af1, B0, acc[1][0], 0, 0, 0); \
        acc[1][1] = __builtin_amdgcn_mfma_f32_16x16x32_bf16(af1, B1, acc[1][1], 0, 0, 0); \
        acc[1][2] = __builtin_amdgcn_mfma_f32_16x16x32_bf16(af1, B2, acc[1][2], 0, 0, 0); \
        acc[1][3] = __builtin_amdgcn_mfma_f32_16x16x32_bf16(af1, B3, acc[1][3], 0, 0, 0); \
    } while (0)

    LOAD_A(0);
    LOADB(0, BP0, BP1, BP2, BP3);

    for (int it = 0; it < TOTAL_IT; it += 2) {
        // even: stage A(it), prefetch A(it+1)+B(it+1), compute with BP
        __syncthreads();
        STAGE_A();
        __syncthreads();
        LOAD_A(it + 1);
        LOADB(it + 1, BQ0, BQ1, BQ2, BQ3);
        DO_MFMA(BP0, BP1, BP2, BP3);
        // odd: stage A(it+1), prefetch A(it+2)+B(it+2), compute with BQ
        __syncthreads();
        STAGE_A();
        __syncthreads();
        if (it + 2 < TOTAL_IT) {
            LOAD_A(it + 2);
            LOADB(it + 2, BP0, BP1, BP2, BP3);
        }
        DO_MFMA(BQ0, BQ1, BQ2, BQ3);
    }
#undef DO_MFMA
#undef STAGE_A
#undef LOADB
#undef LOAD_A

    #pragma unroll
    for (int tm = 0; tm < TM; ++tm) {
        #pragma unroll
        for (int tn = 0; tn < 4; ++tn) {
            const int col = colbase + tn*16 + l16;
            const float bv = HAS_BIAS ? bias[col] : 0.0f;
            #pragma unroll
            for (int rg = 0; rg < 4; ++rg) {
                const int m = mbase + tm*16 + q*4 + rg;
                const int pix = pixbase + m;
                const int oh = pix >> 5, ow = pix & 31;
                size_t oidx = (((size_t)n_img * Hout + (oh*OS + oph)) * Wout
                               + (ow*OS + opw)) * COUT + col;
                float v = acc[tm][tn][rg] + bv;
                if (RESID) v += bf2f(out[oidx]);
                if (RELU_OUT) v = fmaxf(v, 0.0f);
                out[oidx] = f2bf(v);
            }
        }
    }
}

// ---------------- fused residual block ----------------
// R7: loop1 B global->register (BP/BQ, x2 unroll); A staging unchanged.
// Second 1x1 GEMM (b2T in LDS) and epilogues unchanged. FRELU as R2.
template<bool FRELU>
__global__ __launch_bounds__(256)
void res_fused_k(const u16* __restrict__ in, const u16* __restrict__ w1,
                 const u16* __restrict__ w2, u16* __restrict__ out)
{
    constexpr int LDA = 40;
    __shared__ alignas(16) u16 smem[20480];   // 40KB
    u16* aT   = smem;
    u16* mT0  = smem;
    u16* mT1  = smem + 5120;
    u16* b2T0 = smem + 10240;
    u16* b2T1 = smem + 15360;

    const int tid = threadIdx.x;
    const int m0 = swz512(blockIdx.x) * 128;
    const int n_img = m0 >> 10;
    const int pixbase = m0 & 1023;

    const int r = tid >> 1, half = tid & 1;
    const int pr = pixbase + r;
    const int ohr = pr >> 5, owr = pr & 31;
    const u16* inb = in + (size_t)n_img * 1024 * 128;

    const int wv = tid >> 6, lane = tid & 63;
    const int q = lane >> 4, l16 = lane & 15;
    const int mbase = wv * 32;

    {
        const u16* s = w2 + r * 64 + half * 32;
        u16* d = (half ? b2T1 : b2T0) + r * LDA;
        *(uint4*)(d)      = *(const uint4*)(s);
        *(uint4*)(d + 8)  = *(const uint4*)(s + 8);
        *(uint4*)(d + 16) = *(const uint4*)(s + 16);
        *(uint4*)(d + 24) = *(const uint4*)(s + 24);
    }

    f32x4 acc[2][4] = {};
    uint4 pa0, pa1;
    bf16x8 BP0, BP1, BP2, BP3, BQ0, BQ1, BQ2, BQ3;

#define RLOAD_A(IT) do {                                                        \
        int t_ = (IT) >> 2, cc_ = ((IT) & 3) * 32;                              \
        int ih_ = ohr + t_/3 - 1, iw_ = owr + t_%3 - 1;                         \
        bool ok_ = ((unsigned)ih_ < 32u) && ((unsigned)iw_ < 32u);              \
        pa0 = (uint4){0,0,0,0}; pa1 = (uint4){0,0,0,0};                         \
        if (ok_) {                                                              \
            const u16* as_ = inb + ((size_t)ih_ * 32 + iw_) * 128               \
                             + half * 16 + cc_;                                 \
            pa0 = *(const uint4*)(as_);                                         \
            pa1 = *(const uint4*)(as_ + 8);                                     \
        }                                                                       \
    } while (0)

#define RLOADB(IT, B0, B1, B2, B3) do {                                         \
        int t_ = (IT) >> 2, cc_ = ((IT) & 3) * 32;                              \
        const u16* wb_ = w1 + ((size_t)t_ * 64 + l16) * 128 + cc_ + q * 8;      \
        B0 = *(const bf16x8*)(wb_);                                             \
        B1 = *(const bf16x8*)(wb_ + (size_t)16 * 128);                          \
        B2 = *(const bf16x8*)(wb_ + (size_t)32 * 128);                          \
        B3 = *(const bf16x8*)(wb_ + (size_t)48 * 128);                          \
    } while (0)

#define RSTAGE_A() do {                                                         \
        uint4 a0 = pa0, a1 = pa1;                                               \
        a0.x = relu2(a0.x); a0.y = relu2(a0.y);                                 \
        a0.z = relu2(a0.z); a0.w = relu2(a0.w);                                 \
        a1.x = relu2(a1.x); a1.y = relu2(a1.y);                                 \
        a1.z = relu2(a1.z); a1.w = relu2(a1.w);                                 \
        *(uint4*)&aT[r * LDA + half * 16]     = a0;                             \
        *(uint4*)&aT[r * LDA + half * 16 + 8] = a1;                             \
    } while (0)

#define RDO_MFMA(B0, B1, B2, B3) do {                                           \
        bf16x8 af0 = *(const bf16x8*)&aT[(mbase + l16) * LDA + q * 8];          \
        bf16x8 af1 = *(const bf16x8*)&aT[(mbase + 16 + l16) * LDA + q * 8];     \
        acc[0][0] = __builtin_amdgcn_mfma_f32_16x16x32_bf16(af0, B0, acc[0][0], 0, 0, 0); \
        acc[0][1] = __builtin_amdgcn_mfma_f32_16x16x32_bf16(af0, B1, acc[0][1], 0, 0, 0); \
        acc[0][2] = __builtin_amdgcn_mfma_f32_16x16x32_bf16(af0, B2, acc[0][2], 0, 0, 0); \
        acc[0][3] = __builtin_amdgcn_mfma_f32_16x16x32_bf16(af0, B3, acc[0][3], 0, 0, 0); \
        acc[1][0] = __builtin_amdgcn_mfma_f32_16x16x32_bf16(af1, B0, acc[1][0], 0, 0, 0); \
        acc[1][1] = __builtin_amdgcn_mfma_f32_16x16x32_bf16(af1, B1, acc[1][1], 0, 0, 0); \
        acc[1][2] = __builtin_amdgcn_mfma_f32_16x16x32_bf16(af1, B2, acc[1][2], 0, 0, 0); \
        acc[1][3] = __builtin_amdgcn_mfma_f32_16x16x32_bf16(af1, B3, acc[1][3], 0, 0, 0); \
    } while (0)

    RLOAD_A(0);
    RLOADB(0, BP0, BP1, BP2, BP3);

    for (int it = 0; it < 36; it += 2) {
        __syncthreads();
        RSTAGE_A();
        __syncthreads();
        RLOAD_A(it + 1);
        RLOADB(it + 1, BQ0, BQ1, BQ2, BQ3);
        RDO_MFMA(BP0, BP1, BP2, BP3);

        __syncthreads();
        RSTAGE_A();
        __syncthreads();
        if (it + 2 < 36) {
            RLOAD_A(it + 2);
            RLOADB(it + 2, BP0, BP1, BP2, BP3);
        }
        RDO_MFMA(BQ0, BQ1, BQ2, BQ3);
    }
#undef RDO_MFMA
#undef RSTAGE_A
#undef RLOADB
#undef RLOAD_A

    __syncthreads();

    #pragma unroll
    for (int tm = 0; tm < 2; ++tm)
        #pragma unroll
        for (int tn = 0; tn < 4; ++tn) {
            u16* dst = (tn < 2) ? mT0 : mT1;
            const int kc = (tn & 1) * 16 + l16;
            #pragma unroll
            for (int rg = 0; rg < 4; ++rg) {
                int row = mbase + tm*16 + q*4 + rg;
                dst[row * LDA + kc] = f2bf(fmaxf(acc[tm][tn][rg], 0.0f));
            }
        }
    __syncthreads();

    f32x4 acc2[2][8] = {};
    #pragma unroll
    for (int kk = 0; kk < 2; ++kk) {
        const u16* mp = kk ? mT1 : mT0;
        const u16* bp = kk ? b2T1 : b2T0;
        bf16x8 af[2], bf[8];
        #pragma unroll
        for (int tm = 0; tm < 2; ++tm)
            af[tm] = *(const bf16x8*)&mp[(mbase + tm*16 + l16) * LDA + q * 8];
        #pragma unroll
        for (int tn = 0; tn < 8; ++tn)
            bf[tn] = *(const bf16x8*)&bp[(tn*16 + l16) * LDA + q * 8];
        #pragma unroll
        for (int tm = 0; tm < 2; ++tm)
            #pragma unroll
            for (int tn = 0; tn < 8; ++tn)
                acc2[tm][tn] = __builtin_amdgcn_mfma_f32_16x16x32_bf16(
                    af[tm], bf[tn], acc2[tm][tn], 0, 0, 0);
    }

    #pragma unroll
    for (int tm = 0; tm < 2; ++tm)
        #pragma unroll
        for (int tn = 0; tn < 8; ++tn) {
            const int col = tn*16 + l16;
            #pragma unroll
            for (int rg = 0; rg < 4; ++rg) {
                const int m = mbase + tm*16 + q*4 + rg;
                const int pix = pixbase + m;
                size_t off = ((size_t)n_img * 1024 + pix) * 128 + col;
                float v = acc2[tm][tn][rg] + bf2f(in[off]);
                if (FRELU) v = fmaxf(v, 0.0f);
                out[off] = f2bf(v);
            }
        }
}

// ---------------- fused enc_adj (1x1 128->64) + VQ ----------------
__global__ __launch_bounds__(256)
void adjvq_k(const u16* __restrict__ TRin, const u16* __restrict__ wadj,
             const float* __restrict__ bias, const u16* __restrict__ Ebf,
             const float* __restrict__ enorm1, u16* __restrict__ Zq,
             u16* __restrict__ idx_out, float* __restrict__ sse)
{
    constexpr int LDA = 40;
    __shared__ alignas(16) u16 smem[18432];   // 36.9KB aliased region
    u16* aT  = smem;             // [0,5120)   phase A
    u16* bT  = smem + 5120;      // [5120,7680)
    u16* mT0 = smem;             // [0,5120)   Ze k0..31
    u16* mT1 = smem + 5120;      // [5120,10240) Ze k32..63
    u16* eld = smem;             // [0,18432)  codebook pass
    __shared__ float znorm_s[128];
    __shared__ float bestf_s[128];
    __shared__ float en1s[256];
    __shared__ int   bestk_s[128];
    __shared__ float red[256];

    const int tid = threadIdx.x;
    const int r = tid >> 1, half = tid & 1;
    const int bx = swz512(blockIdx.x);
    const size_t gp = (size_t)bx * 128 + r;
    const u16* arow = TRin + gp * 128 + half * 16;
    const u16* brow = wadj + (size_t)r * 128 + half * 16;

    const int wv = tid >> 6, lane = tid & 63;
    const int q = lane >> 4, l16 = lane & 15;
    const int mbase = wv * 32;

    // ---- phase A: 1x1 conv (input already relu'd) ----
    f32x4 acc[2][4] = {};
    for (int c0 = 0; c0 < 128; c0 += 32) {
        __syncthreads();
        uint4 a0 = *(const uint4*)(arow + c0);
        uint4 a1 = *(const uint4*)(arow + c0 + 8);
        *(uint4*)&aT[r * LDA + half * 16]     = a0;
        *(uint4*)&aT[r * LDA + half * 16 + 8] = a1;
        if (r < 64) {
            *(uint4*)&bT[r * LDA + half * 16]     = *(const uint4*)(brow + c0);
            *(uint4*)&bT[r * LDA + half * 16 + 8] = *(const uint4*)(brow + c0 + 8);
        }
        __syncthreads();
        bf16x8 afr[2], bfr[4];
        #pragma unroll
        for (int tm = 0; tm < 2; ++tm)
            afr[tm] = *(const bf16x8*)&aT[(mbase + tm*16 + l16) * LDA + q * 8];
        #pragma unroll
        for (int tn = 0; tn < 4; ++tn)
            bfr[tn] = *(const bf16x8*)&bT[(tn*16 + l16) * LDA + q * 8];
        #pragma unroll
        for (int tm = 0; tm < 2; ++tm)
            #pragma unroll
            for (int tn = 0; tn < 4; ++tn)
                acc[tm][tn] = __builtin_amdgcn_mfma_f32_16x16x32_bf16(
                    afr[tm], bfr[tn], acc[tm][tn], 0, 0, 0);
    }

    // bias + znorm (fp32) per row
    float zn[2][4] = {};   // [tm][rg]
    #pragma unroll
    for (int tm = 0; tm < 2; ++tm)
        #pragma unroll
        for (int tn = 0; tn < 4; ++tn) {
            const float bv = bias[tn*16 + l16];
            #pragma unroll
            for (int rg = 0; rg < 4; ++rg) {
                float z = acc[tm][tn][rg] + bv;
                acc[tm][tn][rg] = z;
                zn[tm][rg] = fmaf(z, z, zn[tm][rg]);
            }
        }
    #pragma unroll
    for (int m = 1; m < 16; m <<= 1)
        #pragma unroll
        for (int tm = 0; tm < 2; ++tm)
            #pragma unroll
            for (int rg = 0; rg < 4; ++rg)
                zn[tm][rg] += __shfl_xor(zn[tm][rg], m, 64);

    __syncthreads();   // all phase-A LDS reads done before mT overwrite

    #pragma unroll
    for (int tm = 0; tm < 2; ++tm) {
        #pragma unroll
        for (int tn = 0; tn < 4; ++tn) {
            u16* dst = (tn < 2) ? mT0 : mT1;
            const int kc = (tn & 1) * 16 + l16;
            #pragma unroll
            for (int rg = 0; rg < 4; ++rg) {
                int row = mbase + tm*16 + q*4 + rg;
                dst[row * LDA + kc] = f2bf(acc[tm][tn][rg]);
            }
        }
        if (l16 == 0)
            #pragma unroll
            for (int rg = 0; rg < 4; ++rg)
                znorm_s[mbase + tm*16 + q*4 + rg] = zn[tm][rg];
    }
    __syncthreads();

    // Ze A-fragments (rows mbase..mbase+31)
    bf16x8 alo[2], ahi[2];
    #pragma unroll
    for (int tile = 0; tile < 2; ++tile) {
        alo[tile] = *(const bf16x8*)&mT0[(mbase + tile*16 + l16) * LDA + q * 8];
        ahi[tile] = *(const bf16x8*)&mT1[(mbase + tile*16 + l16) * LDA + q * 8];
    }

    // ---- VQ ----
    unsigned key[2][4] = {{0xFFFFFFFFu,0xFFFFFFFFu,0xFFFFFFFFu,0xFFFFFFFFu},
                          {0xFFFFFFFFu,0xFFFFFFFFu,0xFFFFFFFFu,0xFFFFFFFFu}};
    float fb[2][4] = {{1e30f,1e30f,1e30f,1e30f},{1e30f,1e30f,1e30f,1e30f}};

    for (int k0 = 0; k0 < 512; k0 += 256) {
        __syncthreads();
        const uint4* src = (const uint4*)(Ebf + k0 * 64);
        #pragma unroll
        for (int i = tid; i < 2048; i += 256) {
            int row = i >> 3, sub = i & 7;
            *(uint4*)&eld[row * 72 + sub * 8] = src[i];
        }
        en1s[tid] = enorm1[k0 + tid];
        __syncthreads();

        for (int t = 0; t < 16; ++t) {
            const int nl = t * 16 + l16;
            bf16x8 b0 = *(const bf16x8*)&eld[nl * 72 + q * 8];
            bf16x8 b1 = *(const bf16x8*)&eld[nl * 72 + 32 + q * 8];
            const float en1 = en1s[nl];
            const unsigned ng = (unsigned)(k0 + nl);
            #pragma unroll
            for (int tile = 0; tile < 2; ++tile) {
                f32x4 sc4 = {0.0f, 0.0f, 0.0f, 0.0f};
                sc4 = __builtin_amdgcn_mfma_f32_16x16x32_bf16(alo[tile], b0, sc4, 0, 0, 0);
                sc4 = __builtin_amdgcn_mfma_f32_16x16x32_bf16(ahi[tile], b1, sc4, 0, 0, 0);
                #pragma unroll
                for (int rg = 0; rg < 4; ++rg) {
                    float sc = fmaf(sc4[rg], -2.0f, en1);
                    unsigned kk2 = (__float_as_uint(sc) & 0xFFFFFE00u) | ng;
                    key[tile][rg] = min(key[tile][rg], kk2);
                    fb[tile][rg] = fminf(fb[tile][rg], sc);
                }
            }
        }
    }

    #pragma unroll
    for (int m = 1; m < 16; m <<= 1)
        #pragma unroll
        for (int tile = 0; tile < 2; ++tile)
            #pragma unroll
            for (int rg = 0; rg < 4; ++rg) {
                unsigned o = (unsigned)__shfl_xor((int)key[tile][rg], m, 64);
                key[tile][rg] = min(key[tile][rg], o);
                float of = __shfl_xor(fb[tile][rg], m, 64);
                fb[tile][rg] = fminf(fb[tile][rg], of);
            }
    if (l16 == 0)
        #pragma unroll
        for (int tile = 0; tile < 2; ++tile)
            #pragma unroll
            for (int rg = 0; rg < 4; ++rg) {
                int row = mbase + tile*16 + q*4 + rg;
                bestk_s[row] = (int)(key[tile][rg] & 511u);
                bestf_s[row] = fb[tile][rg];
            }
    __syncthreads();

    // epilogue: Zq copy + idx + SSE
    const int pos = tid >> 1, seg = tid & 1;
    const size_t p = (size_t)bx * 128 + pos;
    const int k = bestk_s[pos];
    const u16* ep = Ebf + (size_t)k * 64 + seg * 32;
    u16* qp = Zq + p * 64 + seg * 32;
    #pragma unroll
    for (int h = 0; h < 4; ++h)
        *(uint4*)(qp + h * 8) = *(const uint4*)(ep + h * 8);
    if (seg == 0) idx_out[p] = (u16)k;
    red[tid] = (seg == 0) ? (znorm_s[pos] + bestf_s[pos] - 1.0f) : 0.0f;
    __syncthreads();
    for (int s = 128; s > 0; s >>= 1) {
        if (tid < s) red[tid] += red[tid + s];
        __syncthreads();
    }
    if (tid == 0) atomicAdd(sse, red[0]);
}

// ---------------- conv1 as MFMA im2col GEMM ----------------
__global__ __launch_bounds__(256)
void conv1_mfma_k(const float* __restrict__ x, const u16* __restrict__ wc1b,
                  const float* __restrict__ b, u16* __restrict__ out)
{
    __shared__ alignas(16) u16 smem[15360];
    u16* aT0 = smem;
    u16* aT1 = smem + 5120;
    u16* bT0 = smem + 10240;
    u16* bT1 = smem + 12800;

    const int tid = threadIdx.x;
    const int gbase = blockIdx.x * 128;
    const int r = tid >> 1, half = tid & 1;
    const int p = gbase + r;
    const int ow = p & 63, oh = (p >> 6) & 63, n = p >> 12;
    const float* xb = x + (size_t)n * 3 * 16384;

    {
        int row = tid >> 2, sub = tid & 3;
        *(uint4*)&bT0[row*40 + sub*8] = *(const uint4*)(wc1b + row*64 + sub*8);
        *(uint4*)&bT1[row*40 + sub*8] = *(const uint4*)(wc1b + row*64 + 32 + sub*8);
    }

    float vals[24];
    const int kb = half * 24;
    #pragma unroll
    for (int j = 0; j < 24; ++j) {
        int k = kb + j;
        int ci = k >> 4, kh = (k >> 2) & 3, kw = k & 3;
        int ih = oh*2 - 1 + kh, iw = ow*2 - 1 + kw;
        bool ok = ((unsigned)ih < 128u) && ((unsigned)iw < 128u);
        vals[j] = ok ? xb[ci*16384 + ih*128 + iw] : 0.0f;
    }
    unsigned pk[12];
    #pragma unroll
    for (int jj = 0; jj < 12; ++jj)
        pk[jj] = (unsigned)f2bf(vals[2*jj]) | ((unsigned)f2bf(vals[2*jj+1]) << 16);
    unsigned* a0row = (unsigned*)&aT0[r * 40];
    unsigned* a1row = (unsigned*)&aT1[r * 40];
    if (half == 0) {
        #pragma unroll
        for (int jj = 0; jj < 12; ++jj) a0row[jj] = pk[jj];
    } else {
        a0row[12] = pk[0]; a0row[13] = pk[1];
        a0row[14] = pk[2]; a0row[15] = pk[3];
        #pragma unroll
        for (int jj = 4; jj < 12; ++jj) a1row[jj - 4] = pk[jj];
        *(uint4*)&aT1[r*40 + 16] = (uint4){0,0,0,0};
        *(uint4*)&aT1[r*40 + 24] = (uint4){0,0,0,0};
    }
    __syncthreads();

    const int wv = tid >> 6, lane = tid & 63;
    const int q = lane >> 4, l16 = lane & 15;
    const int mbase = wv * 32;

    f32x4 acc[2][4] = {};
    bf16x8 af0[2], af1[2], bf0[4], bf1[4];
    #pragma unroll
    for (int tm = 0; tm < 2; ++tm) {
        af0[tm] = *(const bf16x8*)&aT0[(mbase + tm*16 + l16) * 40 + q * 8];
        af1[tm] = *(const bf16x8*)&aT1[(mbase + tm*16 + l16) * 40 + q * 8];
    }
    #pragma unroll
    for (int tn = 0; tn < 4; ++tn) {
        bf0[tn] = *(const bf16x8*)&bT0[(tn*16 + l16) * 40 + q * 8];
        bf1[tn] = *(const bf16x8*)&bT1[(tn*16 + l16) * 40 + q * 8];
    }
    #pragma unroll
    for (int tm = 0; tm < 2; ++tm)
        #pragma unroll
        for (int tn = 0; tn < 4; ++tn) {
            acc[tm][tn] = __builtin_amdgcn_mfma_f32_16x16x32_bf16(
                af0[tm], bf0[tn], acc[tm][tn], 0, 0, 0);
            acc[tm][tn] = __builtin_amdgcn_mfma_f32_16x16x32_bf16(
                af1[tm], bf1[tn], acc[tm][tn], 0, 0, 0);
        }

    float bv[4];
    #pragma unroll
    for (int tn = 0; tn < 4; ++tn) bv[tn] = b[tn*16 + l16];

    __syncthreads();
    u16* cbuf = smem;
    #pragma unroll
    for (int tm = 0; tm < 2; ++tm)
        #pragma unroll
        for (int tn = 0; tn < 4; ++tn)
            #pragma unroll
            for (int rg = 0; rg < 4; ++rg) {
                int row = mbase + tm*16 + q*4 + rg;
                int col = tn*16 + l16;
                cbuf[row*72 + col] = f2bf(fmaxf(acc[tm][tn][rg] + bv[tn], 0.0f));
            }
    __syncthreads();

    u16* ob = out + (size_t)gbase * 64;
    #pragma unroll
    for (int it = 0; it < 4; ++it) {
        int j = it * 256 + tid;
        uint4 v = *(const uint4*)&cbuf[(j >> 3) * 72 + (j & 7) * 8];
        *(uint4*)(ob + j * 8) = v;
    }
}

// ---------------- tc2 as MFMA parity GEMM ----------------
// R7: B frag read directly from global (2KB/tap slice, L1-hot); bT removed.
__global__ __launch_bounds__(256)
void tc2_mfma_k(const u16* __restrict__ in, const u16* __restrict__ wT,
                const float* __restrict__ bias, float* __restrict__ out)
{
    constexpr int LDA = 40;
    __shared__ alignas(16) u16 aT[128 * LDA];
    __shared__ float cT[128 * 17];

    const int tid = threadIdx.x;
    const int m0 = blockIdx.x * 128;
    const int n_img = m0 >> 12;
    const int pixbase = m0 & 4095;
    const int y0 = pixbase >> 6;

    const int r = tid >> 1, half = tid & 1;
    const int pr = pixbase + r;
    const int yr = pr >> 6, xr = pr & 63;
    const u16* inb = in + (size_t)n_img * 4096 * 64;

    const int wv = tid >> 6, lane = tid & 63;
    const int q = lane >> 4, l16 = lane & 15;
    const int mbase = wv * 32;

    f32x4 acc[2] = {};

    for (int t = 0; t < 9; ++t) {
        const int ih = yr + t/3 - 1;
        const int iw = xr + t%3 - 1;
        const bool ok = ((unsigned)ih < 64u) && ((unsigned)iw < 64u);
        const u16* asrc = ok ? (inb + ((size_t)ih * 64 + iw) * 64 + half * 16) : inb;

        for (int c0 = 0; c0 < 64; c0 += 32) {
            // B frag straight from global (issued early, used after barrier)
            bf16x8 bf = *(const bf16x8*)(wT + ((size_t)t * 16 + l16) * 64
                                         + c0 + q * 8);
            __syncthreads();
            uint4 a0 = {0,0,0,0}, a1 = {0,0,0,0};
            if (ok) {
                a0 = *(const uint4*)(asrc + c0);
                a1 = *(const uint4*)(asrc + c0 + 8);
            }
            *(uint4*)&aT[r * LDA + half * 16]     = a0;
            *(uint4*)&aT[r * LDA + half * 16 + 8] = a1;
            __syncthreads();

            bf16x8 af0 = *(const bf16x8*)&aT[(mbase + l16) * LDA + q * 8];
            bf16x8 af1 = *(const bf16x8*)&aT[(mbase + 16 + l16) * LDA + q * 8];
            acc[0] = __builtin_amdgcn_mfma_f32_16x16x32_bf16(af0, bf, acc[0], 0, 0, 0);
            acc[1] = __builtin_amdgcn_mfma_f32_16x16x32_bf16(af1, bf, acc[1], 0, 0, 0);
        }
    }

    __syncthreads();
    #pragma unroll
    for (int tm = 0; tm < 2; ++tm)
        #pragma unroll
        for (int rg = 0; rg < 4; ++rg)
            cT[(mbase + tm*16 + q*4 + rg) * 17 + l16] = acc[tm][rg];
    __syncthreads();

    #pragma unroll
    for (int it = 0; it < 6; ++it) {
        int j = it * 256 + tid;
        int co  = j >> 9;
        int rem = j & 511;
        int ohl = rem >> 7;
        int ow  = rem & 127;
        int oh  = 2*y0 + ohl;
        int lp  = (ohl >> 1) * 64 + (ow >> 1);
        int col = ((ohl & 1) * 2 + (ow & 1)) * 4 + co;
        float v = cT[lp * 17 + col] + bias[co];
        out[(((size_t)n_img * 3 + co) * 128 + oh) * 128 + ow] = v;
    }
}

// ---------------- histogram by scan ----------------
__global__ __launch_bounds__(256)
void hist_k(const u16* __restrict__ idx, float* __restrict__ counts)
{
    __shared__ int red[256];
    const int k = blockIdx.x;
    const int tid = threadIdx.x;
    int c = 0;
    const uint4* p4 = (const uint4*)idx;
    for (int i = tid; i < 8192; i += 256) {
        uint4 v = p4[i];
        unsigned ua[4] = {v.x, v.y, v.z, v.w};
        #pragma unroll
        for (int j = 0; j < 4; ++j) {
            c += ((ua[j] & 0xFFFFu) == (unsigned)k);
            c += ((ua[j] >> 16)     == (unsigned)k);
        }
    }
    red[tid] = c;
    __syncthreads();
    for (int s = 128; s > 0; s >>= 1) {
        if (tid < s) red[tid] += red[tid + s];
        __syncthreads();
    }
    if (tid == 0) counts[k] = (float)red[0];
}

// ---------------- merged prep ----------------
__device__ __forceinline__ void wconv_tf(const float* __restrict__ w,
                                         u16* __restrict__ o,
                                         int COUT, int CIN, int KK, int i)
{
    int ci = i % CIN; int t = i / CIN; int co = t % COUT; t /= COUT;
    o[i] = f2bf(w[(co*CIN + ci)*KK + t]);
}

__global__ __launch_bounds__(256)
void prep_k(const float* __restrict__ enc_w1, const float* __restrict__ enc_w2,
            const float* __restrict__ enc_w3, const float* __restrict__ enc_w4,
            const float* __restrict__ enc_res_w1, const float* __restrict__ enc_res_w2,
            const float* __restrict__ dec_res_w1, const float* __restrict__ dec_res_w2,
            const float* __restrict__ enc_adj_w, const float* __restrict__ dec_adj_w,
            const float* __restrict__ tc1_w, const float* __restrict__ tc2_w,
            const float* __restrict__ E,
            u16* __restrict__ wc1b, u16* __restrict__ wc2, u16* __restrict__ wc3,
            u16* __restrict__ wc4, u16* __restrict__ wer1, u16* __restrict__ wer2,
            u16* __restrict__ wdr1, u16* __restrict__ wdr2, u16* __restrict__ weadj,
            u16* __restrict__ wdadj, u16* __restrict__ wtc1, u16* __restrict__ wtc2b,
            u16* __restrict__ Ebf, float* __restrict__ enorm1, float* __restrict__ sse)
{
    const int b = blockIdx.x, tid = threadIdx.x;
    if (b < 512) {
        wconv_tf(enc_w2, wc2, 128, 64, 16, b * 256 + tid);
    } else if (b < 1088) {
        wconv_tf(enc_w3, wc3, 128, 128, 9, (b - 512) * 256 + tid);
    } else if (b < 1664) {
        wconv_tf(enc_w4, wc4, 128, 128, 9, (b - 1088) * 256 + tid);
    } else if (b < 2240) {
        int i = (b - 1664) * 256 + tid;
        int sub = i / 73728, rem = i - sub * 73728;
        wconv_tf(enc_res_w1 + sub * 73728, wer1 + sub * 73728, 64, 128, 9, rem);
    } else if (b < 2816) {
        int i = (b - 2240) * 256 + tid;
        int sub = i / 73728, rem = i - sub * 73728;
        wconv_tf(dec_res_w1 + sub * 73728, wdr1 + sub * 73728, 64, 128, 9, rem);
    } else if (b < 2880) {
        int i = (b - 2816) * 256 + tid;
        int sub = i >> 13, rem = i & 8191;
        wconv_tf(enc_res_w2 + sub * 8192, wer2 + sub * 8192, 128, 64, 1, rem);
    } else if (b < 2944) {
        int i = (b - 2880) * 256 + tid;
        int sub = i >> 13, rem = i & 8191;
        wconv_tf(dec_res_w2 + sub * 8192, wdr2 + sub * 8192, 128, 64, 1, rem);
    } else if (b < 2976) {
        wconv_tf(enc_adj_w, weadj, 64, 128, 1, (b - 2944) * 256 + tid);
    } else if (b < 3264) {
        wconv_tf(dec_adj_w, wdadj, 128, 64, 9, (b - 2976) * 256 + tid);
    } else if (b < 3776) {
        int i = (b - 3264) * 256 + tid;
        int ci = i & 127; int co = (i >> 7) & 63; int t = (i >> 13) & 3; int p = i >> 15;
        int poh = p >> 1, pw = p & 1; int a = t >> 1, bb = t & 1;
        int kh = poh ? (a ? 2 : 0) : (a ? 3 : 1);
        int kw = pw  ? (bb ? 2 : 0) : (bb ? 3 : 1);
        wtc1[i] = f2bf(tc1_w[((ci*64 + co)*4 + kh)*4 + kw]);
    } else if (b < 3812) {
        int i = (b - 3776) * 256 + tid;
        int ci = i & 63; int col = (i >> 6) & 15; int t = i >> 10;
        int dh = t / 3 - 1, dw = t % 3 - 1;
        int pp = col >> 2, co = col & 3;
        float v = 0.0f;
        if (co < 3) {
            int poh = pp >> 1, pw = pp & 1;
            int kh = poh ? (dh == 1 ? 0 : (dh == 0 ? 2 : -1))
                         : (dh == 0 ? 1 : (dh == -1 ? 3 : -1));
            int kw = pw  ? (dw == 1 ? 0 : (dw == 0 ? 2 : -1))
                         : (dw == 0 ? 1 : (dw == -1 ? 3 : -1));
            if (kh >= 0 && kw >= 0)
                v = tc2_w[((ci*3 + co)*4 + kh)*4 + kw];
        }
        wtc2b[i] = f2bf(v);
    } else if (b < 3814) {
        int k = (b - 3812) * 256 + tid;
        float s = 0.0f;
        #pragma unroll
        for (int d = 0; d < 64; ++d) {
            u16 h = f2bf(E[k*64 + d]);
            Ebf[k*64 + d] = h;
            float v = bf2f(h);
            s = fmaf(v, v, s);
        }
        enorm1[k] = s + 1.0f;
    } else if (b < 3830) {
        int i = (b - 3814) * 256 + tid;
        int co = i >> 6, k = i & 63;
        float v = 0.0f;
        if (k < 48) {
            int ci = k >> 4, kh = (k >> 2) & 3, kw = k & 3;
            v = enc_w1[((co*3 + ci)*4 + kh)*4 + kw];
        }
        wc1b[i] = f2bf(v);
    } else {
        if (tid == 0) sse[0] = 0.0f;
    }
}

// ---------------- scalars ----------------
__global__ void finalize_k(const float* __restrict__ counts, const float* __restrict__ sse,
                           float* __restrict__ out_head, float* __restrict__ out_tail)
{
    __shared__ float red[512];
    int t = threadIdx.x;
    float pr = counts[t] / 65536.0f;
    red[t] = -pr * log2f(pr + 1e-10f);
    __syncthreads();
    for (int s = 256; s > 0; s >>= 1) {
        if (t < s) red[t] += red[t + s];
        __syncthreads();
    }
    if (t == 0) {
        float entropy = red[0];
        float mse = sse[0] / 4194304.0f;
        out_head[0] = 1.25f * mse;
        out_tail[0] = mse;
        out_tail[1] = mse;
        out_tail[2] = exp2f(entropy);
    }
}

// ---------------------------------------------------------------------------
extern "C" void kernel_launch(void* const* d_in, const int* in_sizes, int n_in,
                              void* d_out, int out_size, void* d_ws, size_t ws_size,
                              hipStream_t stream)
{
    const float* x         = (const float*)d_in[0];
    const float* enc_w1    = (const float*)d_in[1];
    const float* enc_b1    = (const float*)d_in[2];
    const float* enc_w2    = (const float*)d_in[3];
    const float* enc_b2    = (const float*)d_in[4];
    const float* enc_w3    = (const float*)d_in[5];
    const float* enc_b3    = (const float*)d_in[6];
    const float* enc_w4    = (const float*)d_in[7];
    const float* enc_b4    = (const float*)d_in[8];
    const float* enc_res_w1= (const float*)d_in[9];
    const float* enc_res_w2= (const float*)d_in[10];
    const float* enc_adj_w = (const float*)d_in[11];
    const float* enc_adj_b = (const float*)d_in[12];
    const float* Ecb       = (const float*)d_in[13];
    const float* dec_adj_w = (const float*)d_in[14];
    const float* dec_adj_b = (const float*)d_in[15];
    const float* dec_res_w1= (const float*)d_in[16];
    const float* dec_res_w2= (const float*)d_in[17];
    const float* tc1_w     = (const float*)d_in[18];
    const float* tc1_b     = (const float*)d_in[19];
    const float* tc2_w     = (const float*)d_in[20];
    const float* tc2_b     = (const float*)d_in[21];

    char* wsb = (char*)d_ws;
    u16*   wc2   = (u16*)(wsb + 0);
    u16*   wc3   = (u16*)(wsb + 262144);
    u16*   wc4   = (u16*)(wsb + 557056);
    u16*   wer1  = (u16*)(wsb + 851968);
    u16*   wer2  = (u16*)(wsb + 1146880);
    u16*   weadj = (u16*)(wsb + 1179648);
    u16*   wdadj = (u16*)(wsb + 1196032);
    u16*   wdr1  = (u16*)(wsb + 1343488);
    u16*   wdr2  = (u16*)(wsb + 1638400);
    u16*   wtc1  = (u16*)(wsb + 1671168);
    u16*   wtc2b = (u16*)(wsb + 1933312);
    float* counts= (float*)(wsb + 1951744);
    float* sse   = counts + 512;
    u16*   Ebf   = (u16*)(wsb + 1955840);
    float* enorm1= (float*)(wsb + 2021376);
    u16*   wc1b  = (u16*)(wsb + 2023424);
    u16*   H1    = (u16*)(wsb + 2097152);
    u16*   TR    = (u16*)(wsb + 35651584);
    u16*   H3    = (u16*)(wsb + 52428800);
    u16*   ZQ    = (u16*)(wsb + 85983232);
    u16*   IDX   = (u16*)(wsb + 94371840);
    u16*   TC1O  = H1;

    float* out  = (float*)d_out;
    float* xrec = out + 1;
    float* tail = out + 1 + 3145728;

    // ---- single merged prep dispatch ----
    prep_k<<<3831, 256, 0, stream>>>(enc_w1, enc_w2, enc_w3, enc_w4,
        enc_res_w1, enc_res_w2, dec_res_w1, dec_res_w2, enc_adj_w, dec_adj_w,
        tc1_w, tc2_w, Ecb, wc1b, wc2, wc3, wc4, wer1, wer2, wdr1, wdr2,
        weadj, wdadj, wtc1, wtc2b, Ebf, enorm1, sse);

    // ---- encoder ----
    conv1_mfma_k<<<2048, 256, 0, stream>>>(x, wc1b, enc_b1, H1);
    mfma_conv_k<64,128,2,false,true,true,false><<<dim3(512,2), 256, 0, stream>>>
        (H1, wc2, enc_b2, TR, 64, 64, 32, 32, 1);
    mfma_conv_k<128,128,1,false,true,true,false><<<dim3(512,2), 256, 0, stream>>>
        (TR, wc3, enc_b3, H3, 32, 32, 32, 32, 1);
    mfma_conv_k<128,128,1,false,false,true,false><<<dim3(512,2), 256, 0, stream>>>
        (H3, wc4, enc_b4, TR, 32, 32, 32, 32, 1);
    // fused res blocks: TR -> H3 -> TR (2nd block writes post-relu for adjvq)
    res_fused_k<false><<<512, 256, 0, stream>>>(TR, wer1,         wer2,        H3);
    res_fused_k<true ><<<512, 256, 0, stream>>>(H3, wer1 + 73728, wer2 + 8192, TR);

    // ---- fused enc_adj + VQ ----
    adjvq_k<<<512, 256, 0, stream>>>(TR, weadj, enc_adj_b, Ebf, enorm1,
                                     ZQ, IDX, sse);
    hist_k<<<512, 256, 0, stream>>>(IDX, counts);

    // ---- decoder ----
    mfma_conv_k<64,128,1,false,false,true,false><<<dim3(512,2), 256, 0, stream>>>
        (ZQ, wdadj, dec_adj_b, H3, 32, 32, 32, 32, 1);
    // fused res blocks: H3 -> TR -> H3 (2nd block writes post-relu for tc1)
    res_fused_k<false><<<512, 256, 0, stream>>>(H3, wdr1,         wdr2,        TR);
    res_fused_k<true ><<<512, 256, 0, stream>>>(TR, wdr1 + 73728, wdr2 + 8192, H3);
    // tc1: all 4 parities in one dispatch (blockIdx.z); input pre-relu'd
    mfma_conv_k<128,64,3,false,true,true,false><<<dim3(512,1,4), 256, 0, stream>>>
        (H3, wtc1, tc1_b, TC1O, 32, 32, 64, 64, 2);
    tc2_mfma_k<<<2048, 256, 0, stream>>>(TC1O, wtc2b, tc2_b, xrec);

    // ---- scalars ----
    finalize_k<<<1, 512, 0, stream>>>(counts, sse, out, tail);
}

// Round 8
// 434.475 us; speedup vs baseline: 1.7069x; 1.7069x over previous
//
#include <hip/hip_runtime.h>
#include <math.h>

// ---------------------------------------------------------------------------
// VQ-VAE forward: NHWC bf16 trunk, MFMA convs, fused res blocks, fused
// enc_adj+VQ, MFMA im2col conv1, MFMA tc2, single merged prep dispatch.
// R2: XCD swizzle + FRELU fold. [442 us baseline]
// R3..R7 (REVERTED) disproved-limiter ledger: LDS-ratio via big tiles (R3,
//   occupancy death), occupancy via COUT-split x4 (R4), barrier drain (R1),
//   global-A latency depth-2 (R5), B-from-global zero/full prefetch (R6/R7:
//   strided 16-transaction gathers swamp L1/TA). Standing model: R2 is
//   LDS-throughput bound (36KB/block/K-step vs ~40cy MFMA); read side is
//   split-shape-invariant; WRITE side has 2x A redundancy from grid.y split.
// R8: merge the COUT split for COUT=128 convs (conv2/3/4, dec_adj):
//   one 512-thread block = 128px x 128cols, 8 waves in 4x2 grid, per-wave
//   tile unchanged (32x64, TM=2/TN=4). A staged ONCE (LDS writes -11%/CU,
//   A global fetch + addressing halved, barrier pairs halved). Occupancy
//   unchanged (16 waves/CU). tc1/res_fused/rest byte-identical to R2.
//
// Workspace layout (bytes):
//   [0 .. ~2.1MB)   transformed weights + counts/sse + Ebf + enorm1 + wc1b
//   H1  = 2097152   (64,64,64,64)  NHWC bf16  33.5MB   h1, later tc1 out
//   TR  = 35651584  (64,32,32,128) NHWC bf16  16.8MB   trunk ping
//   H3  = 52428800  (64,32,32,128) NHWC bf16  16.8MB   trunk pong
//   ZQ  = 85983232  (64,32,32,64)  NHWC bf16   8.4MB
//   IDX = 94371840  65536 u16      128KB
// ---------------------------------------------------------------------------

typedef unsigned short u16;
typedef __attribute__((ext_vector_type(8))) short bf16x8;
typedef __attribute__((ext_vector_type(4))) float f32x4;

__device__ __forceinline__ float bf2f(u16 h) {
    union { unsigned u; float f; } v; v.u = ((unsigned)h) << 16; return v.f;
}
__device__ __forceinline__ u16 f2bf(float f) {
    union { float f; unsigned u; } v; v.f = f;
    unsigned r = v.u + 0x7FFFu + ((v.u >> 16) & 1u);
    return (u16)(r >> 16);
}
__device__ __forceinline__ unsigned relu2(unsigned x) {
    return x & ~(((x & 0x80008000u) >> 15) * 0xFFFFu);
}
// XCD-aware bijective swizzle for gridX=512 (512 = 8 XCDs * 64 chunks).
__device__ __forceinline__ int swz512(int x) {
    return ((x & 7) << 6) | (x >> 3);
}

// ---------------- merged-COUT implicit-GEMM conv (R8) ----------------
// 512 threads = 8 waves (4 row-tiles x 2 col-tiles), block output
// 128 pixels x 128 cols. Per-wave tile 32x64 (TM=2/TN=4) as R2.
// A+B staged to LDS once per K-step (A no longer duplicated across a
// grid.y split). Depth-1 register prefetch, 2 barriers/step, LDA=40.
// TAPMODE: 0=1x1, 1=3x3, 2=4x4 stride2.
template<int CIN, int TAPMODE, bool RELU_OUT>
__global__ __launch_bounds__(512)
void mfma_conv512_k(const u16* __restrict__ in, const u16* __restrict__ wT,
                    const float* __restrict__ bias, u16* __restrict__ out,
                    int Hin, int Win, int Hout, int Wout)
{
    constexpr int COUT = 128;
    constexpr int LDA = 40;
    constexpr int NCH = CIN / 32;
    constexpr int NTAPS = (TAPMODE == 0) ? 1 : (TAPMODE == 1) ? 9 : 16;
    constexpr int S = (TAPMODE == 2) ? 2 : 1;

    __shared__ alignas(16) u16 aT[128 * LDA];   // 10.2KB
    __shared__ alignas(16) u16 bT[128 * LDA];   // 10.2KB

    const int tid = threadIdx.x;
    const int m0 = swz512(blockIdx.x) * 128;
    const int n_img = m0 >> 10;
    const int pixbase = m0 & 1023;

    // staging: each of 512 threads moves one 16B part of A and one of B
    const int r = tid >> 2, part = tid & 3;
    const int pr = pixbase + r;
    const int ohr = pr >> 5, owr = pr & 31;
    const u16* inb = in + (size_t)n_img * Hin * Win * CIN;

    const int wv = tid >> 6, lane = tid & 63;
    const int q = lane >> 4, l16 = lane & 15;
    const int mbase = (wv & 3) * 32;
    const int colbase = (wv >> 2) * 64;

    f32x4 acc[2][4] = {};

    const int total_it = NTAPS * NCH;
    uint4 pa, pb;

#define LOAD_IT(IT) do {                                                        \
        int t_ = (IT) / NCH, cc_ = ((IT) % NCH) * 32;                           \
        int dh_, dw_;                                                           \
        if (TAPMODE == 0)      { dh_ = 0;           dw_ = 0; }                  \
        else if (TAPMODE == 1) { dh_ = t_/3 - 1;    dw_ = t_%3 - 1; }           \
        else                   { dh_ = (t_>>2) - 1; dw_ = (t_&3) - 1; }         \
        int ih_ = ohr * S + dh_;                                                \
        int iw_ = owr * S + dw_;                                                \
        bool ok_ = ((unsigned)ih_ < (unsigned)Hin) &&                           \
                   ((unsigned)iw_ < (unsigned)Win);                             \
        pa = (uint4){0,0,0,0};                                                  \
        if (ok_)                                                                \
            pa = *(const uint4*)(inb + ((size_t)ih_ * Win + iw_) * CIN          \
                                 + cc_ + part * 8);                             \
        pb = *(const uint4*)(wT + ((size_t)t_ * COUT + r) * CIN                 \
                             + cc_ + part * 8);                                 \
    } while (0)

    LOAD_IT(0);

    for (int it = 0; it < total_it; ++it) {
        __syncthreads();
        *(uint4*)&aT[r * LDA + part * 8] = pa;
        *(uint4*)&bT[r * LDA + part * 8] = pb;
        __syncthreads();
        if (it + 1 < total_it) LOAD_IT(it + 1);   // prefetch overlaps MFMAs

        bf16x8 afr[2], bfr[4];
        #pragma unroll
        for (int tm = 0; tm < 2; ++tm)
            afr[tm] = *(const bf16x8*)&aT[(mbase + tm*16 + l16) * LDA + q * 8];
        #pragma unroll
        for (int tn = 0; tn < 4; ++tn)
            bfr[tn] = *(const bf16x8*)&bT[(colbase + tn*16 + l16) * LDA + q * 8];
        #pragma unroll
        for (int tm = 0; tm < 2; ++tm)
            #pragma unroll
            for (int tn = 0; tn < 4; ++tn)
                acc[tm][tn] = __builtin_amdgcn_mfma_f32_16x16x32_bf16(
                    afr[tm], bfr[tn], acc[tm][tn], 0, 0, 0);
    }
#undef LOAD_IT

    #pragma unroll
    for (int tm = 0; tm < 2; ++tm) {
        #pragma unroll
        for (int tn = 0; tn < 4; ++tn) {
            const int col = colbase + tn*16 + l16;
            const float bv = bias[col];
            #pragma unroll
            for (int rg = 0; rg < 4; ++rg) {
                const int m = mbase + tm*16 + q*4 + rg;
                const int pix = pixbase + m;
                const int oh = pix >> 5, ow = pix & 31;
                size_t oidx = (((size_t)n_img * Hout + oh) * Wout + ow) * COUT
                              + col;
                float v = acc[tm][tn][rg] + bv;
                if (RELU_OUT) v = fmaxf(v, 0.0f);
                out[oidx] = f2bf(v);
            }
        }
    }
}

// ---------------- unified implicit-GEMM MFMA conv (R2 form) ----------------
// Retained for tc1 (TAPMODE=3, COUT=64, PAR4 via blockIdx.z).
template<int CIN, int COUT, int TAPMODE, bool RELU_IN, bool RELU_OUT,
         bool HAS_BIAS, bool RESID>
__global__ __launch_bounds__(256)
void mfma_conv_k(const u16* __restrict__ in, const u16* __restrict__ wT,
                 const float* __restrict__ bias, u16* __restrict__ out,
                 int Hin, int Win, int Hout, int Wout, int OS)
{
    constexpr int TM = 2, TN = 4;
    constexpr int LDA = 40;
    constexpr int NCH = CIN / 32;
    constexpr int NTAPS = (TAPMODE == 0) ? 1 : (TAPMODE == 1) ? 9
                        : (TAPMODE == 2) ? 16 : 4;
    constexpr int S = (TAPMODE == 2) ? 2 : 1;

    __shared__ alignas(16) u16 aT[128 * LDA];
    __shared__ alignas(16) u16 bT[64 * LDA];

    const int tid = threadIdx.x;
    const int m0 = swz512(blockIdx.x) * 128;
    const int colbase = blockIdx.y << 6;
    const int pz = (TAPMODE == 3) ? blockIdx.z : 0;
    const u16* wTb = (TAPMODE == 3) ? wT + (size_t)pz * 4 * COUT * CIN : wT;
    const int oph = (TAPMODE == 3) ? (pz >> 1) : 0;
    const int opw = (TAPMODE == 3) ? (pz & 1) : 0;
    const int n_img = m0 >> 10;
    const int pixbase = m0 & 1023;

    const int r = tid >> 1, half = tid & 1;
    const int pr = pixbase + r;
    const int ohr = pr >> 5, owr = pr & 31;
    const u16* inb = in + (size_t)n_img * Hin * Win * CIN;

    const int wv = tid >> 6, lane = tid & 63;
    const int q = lane >> 4, l16 = lane & 15;
    const int mbase = wv * 32;
    const bool bload = r < 64;

    f32x4 acc[TM][TN] = {};

    const int total_it = NTAPS * NCH;
    uint4 pa0, pa1, pb0 = {0,0,0,0}, pb1 = {0,0,0,0};

#define LOAD_IT(IT) do {                                                        \
        int t_ = (IT) / NCH, cc_ = ((IT) % NCH) * 32;                           \
        int dh_, dw_;                                                           \
        if (TAPMODE == 0)      { dh_ = 0;              dw_ = 0; }               \
        else if (TAPMODE == 1) { dh_ = t_/3 - 1;       dw_ = t_%3 - 1; }        \
        else if (TAPMODE == 2) { dh_ = (t_>>2) - 1;    dw_ = (t_&3) - 1; }      \
        else                   { dh_ = (pz>>1) - (t_>>1); dw_ = (pz&1) - (t_&1); } \
        int ih_ = ohr * S + dh_;                                                \
        int iw_ = owr * S + dw_;                                                \
        bool ok_ = ((unsigned)ih_ < (unsigned)Hin) &&                           \
                   ((unsigned)iw_ < (unsigned)Win);                             \
        pa0 = (uint4){0,0,0,0}; pa1 = (uint4){0,0,0,0};                         \
        if (ok_) {                                                              \
            const u16* as_ = inb + ((size_t)ih_ * Win + iw_) * CIN              \
                             + half * 16 + cc_;                                 \
            pa0 = *(const uint4*)(as_);                                         \
            pa1 = *(const uint4*)(as_ + 8);                                     \
        }                                                                       \
        if (bload) {                                                            \
            const u16* bs_ = wTb + ((size_t)t_ * COUT + colbase + r) * CIN      \
                             + half * 16 + cc_;                                 \
            pb0 = *(const uint4*)(bs_);                                         \
            pb1 = *(const uint4*)(bs_ + 8);                                     \
        }                                                                       \
    } while (0)

    LOAD_IT(0);

    for (int it = 0; it < total_it; ++it) {
        __syncthreads();
        uint4 a0 = pa0, a1 = pa1;
        if (RELU_IN) {
            a0.x = relu2(a0.x); a0.y = relu2(a0.y); a0.z = relu2(a0.z); a0.w = relu2(a0.w);
            a1.x = relu2(a1.x); a1.y = relu2(a1.y); a1.z = relu2(a1.z); a1.w = relu2(a1.w);
        }
        *(uint4*)&aT[r * LDA + half * 16]     = a0;
        *(uint4*)&aT[r * LDA + half * 16 + 8] = a1;
        if (bload) {
            *(uint4*)&bT[r * LDA + half * 16]     = pb0;
            *(uint4*)&bT[r * LDA + half * 16 + 8] = pb1;
        }
        __syncthreads();
        if (it + 1 < total_it) LOAD_IT(it + 1);   // prefetch overlaps MFMAs

        bf16x8 afr[TM], bfr[TN];
        #pragma unroll
        for (int tm = 0; tm < TM; ++tm)
            afr[tm] = *(const bf16x8*)&aT[(mbase + tm*16 + l16) * LDA + q * 8];
        #pragma unroll
        for (int tn = 0; tn < TN; ++tn)
            bfr[tn] = *(const bf16x8*)&bT[(tn*16 + l16) * LDA + q * 8];
        #pragma unroll
        for (int tm = 0; tm < TM; ++tm)
            #pragma unroll
            for (int tn = 0; tn < TN; ++tn)
                acc[tm][tn] = __builtin_amdgcn_mfma_f32_16x16x32_bf16(
                    afr[tm], bfr[tn], acc[tm][tn], 0, 0, 0);
    }
#undef LOAD_IT

    #pragma unroll
    for (int tm = 0; tm < TM; ++tm) {
        #pragma unroll
        for (int tn = 0; tn < TN; ++tn) {
            const int col = colbase + tn*16 + l16;
            const float bv = HAS_BIAS ? bias[col] : 0.0f;
            #pragma unroll
            for (int rg = 0; rg < 4; ++rg) {
                const int m = mbase + tm*16 + q*4 + rg;
                const int pix = pixbase + m;
                const int oh = pix >> 5, ow = pix & 31;
                size_t oidx = (((size_t)n_img * Hout + (oh*OS + oph)) * Wout
                               + (ow*OS + opw)) * COUT + col;
                float v = acc[tm][tn][rg] + bv;
                if (RESID) v += bf2f(out[oidx]);
                if (RELU_OUT) v = fmaxf(v, 0.0f);
                out[oidx] = f2bf(v);
            }
        }
    }
}

// ---------------- fused residual block ----------------
// FRELU: apply relu in the epilogue (only valid when the output feeds a
// consumer that wants post-relu values, i.e. the final block of each stack).
template<bool FRELU>
__global__ __launch_bounds__(256)
void res_fused_k(const u16* __restrict__ in, const u16* __restrict__ w1,
                 const u16* __restrict__ w2, u16* __restrict__ out)
{
    constexpr int LDA = 40;
    __shared__ alignas(16) u16 smem[20480];   // 40KB
    u16* aT   = smem;
    u16* bT   = smem + 5120;
    u16* mT0  = smem;
    u16* mT1  = smem + 5120;
    u16* b2T0 = smem + 10240;
    u16* b2T1 = smem + 15360;

    const int tid = threadIdx.x;
    const int m0 = swz512(blockIdx.x) * 128;
    const int n_img = m0 >> 10;
    const int pixbase = m0 & 1023;

    const int r = tid >> 1, half = tid & 1;
    const int pr = pixbase + r;
    const int ohr = pr >> 5, owr = pr & 31;
    const u16* inb = in + (size_t)n_img * 1024 * 128;

    const int wv = tid >> 6, lane = tid & 63;
    const int q = lane >> 4, l16 = lane & 15;
    const int mbase = wv * 32;
    const bool bload = r < 64;

    {
        const u16* s = w2 + r * 64 + half * 32;
        u16* d = (half ? b2T1 : b2T0) + r * LDA;
        *(uint4*)(d)      = *(const uint4*)(s);
        *(uint4*)(d + 8)  = *(const uint4*)(s + 8);
        *(uint4*)(d + 16) = *(const uint4*)(s + 16);
        *(uint4*)(d + 24) = *(const uint4*)(s + 24);
    }

    f32x4 acc[2][4] = {};
    uint4 pa0, pa1, pb0 = {0,0,0,0}, pb1 = {0,0,0,0};

#define RLOAD(IT) do {                                                          \
        int t_ = (IT) >> 2, cc_ = ((IT) & 3) * 32;                              \
        int ih_ = ohr + t_/3 - 1, iw_ = owr + t_%3 - 1;                         \
        bool ok_ = ((unsigned)ih_ < 32u) && ((unsigned)iw_ < 32u);              \
        pa0 = (uint4){0,0,0,0}; pa1 = (uint4){0,0,0,0};                         \
        if (ok_) {                                                              \
            const u16* as_ = inb + ((size_t)ih_ * 32 + iw_) * 128               \
                             + half * 16 + cc_;                                 \
            pa0 = *(const uint4*)(as_);                                         \
            pa1 = *(const uint4*)(as_ + 8);                                     \
        }                                                                       \
        if (bload) {                                                            \
            const u16* bs_ = w1 + ((size_t)t_ * 64 + r) * 128                   \
                             + half * 16 + cc_;                                 \
            pb0 = *(const uint4*)(bs_);                                         \
            pb1 = *(const uint4*)(bs_ + 8);                                     \
        }                                                                       \
    } while (0)

    RLOAD(0);
    for (int it = 0; it < 36; ++it) {
        __syncthreads();
        uint4 a0 = pa0, a1 = pa1;
        a0.x = relu2(a0.x); a0.y = relu2(a0.y); a0.z = relu2(a0.z); a0.w = relu2(a0.w);
        a1.x = relu2(a1.x); a1.y = relu2(a1.y); a1.z = relu2(a1.z); a1.w = relu2(a1.w);
        *(uint4*)&aT[r * LDA + half * 16]     = a0;
        *(uint4*)&aT[r * LDA + half * 16 + 8] = a1;
        if (bload) {
            *(uint4*)&bT[r * LDA + half * 16]     = pb0;
            *(uint4*)&bT[r * LDA + half * 16 + 8] = pb1;
        }
        __syncthreads();
        if (it + 1 < 36) RLOAD(it + 1);

        bf16x8 afr[2], bfr[4];
        #pragma unroll
        for (int tm = 0; tm < 2; ++tm)
            afr[tm] = *(const bf16x8*)&aT[(mbase + tm*16 + l16) * LDA + q * 8];
        #pragma unroll
        for (int tn = 0; tn < 4; ++tn)
            bfr[tn] = *(const bf16x8*)&bT[(tn*16 + l16) * LDA + q * 8];
        #pragma unroll
        for (int tm = 0; tm < 2; ++tm)
            #pragma unroll
            for (int tn = 0; tn < 4; ++tn)
                acc[tm][tn] = __builtin_amdgcn_mfma_f32_16x16x32_bf16(
                    afr[tm], bfr[tn], acc[tm][tn], 0, 0, 0);
    }
#undef RLOAD

    __syncthreads();

    #pragma unroll
    for (int tm = 0; tm < 2; ++tm)
        #pragma unroll
        for (int tn = 0; tn < 4; ++tn) {
            u16* dst = (tn < 2) ? mT0 : mT1;
            const int kc = (tn & 1) * 16 + l16;
            #pragma unroll
            for (int rg = 0; rg < 4; ++rg) {
                int row = mbase + tm*16 + q*4 + rg;
                dst[row * LDA + kc] = f2bf(fmaxf(acc[tm][tn][rg], 0.0f));
            }
        }
    __syncthreads();

    f32x4 acc2[2][8] = {};
    #pragma unroll
    for (int kk = 0; kk < 2; ++kk) {
        const u16* mp = kk ? mT1 : mT0;
        const u16* bp = kk ? b2T1 : b2T0;
        bf16x8 af[2], bf[8];
        #pragma unroll
        for (int tm = 0; tm < 2; ++tm)
            af[tm] = *(const bf16x8*)&mp[(mbase + tm*16 + l16) * LDA + q * 8];
        #pragma unroll
        for (int tn = 0; tn < 8; ++tn)
            bf[tn] = *(const bf16x8*)&bp[(tn*16 + l16) * LDA + q * 8];
        #pragma unroll
        for (int tm = 0; tm < 2; ++tm)
            #pragma unroll
            for (int tn = 0; tn < 8; ++tn)
                acc2[tm][tn] = __builtin_amdgcn_mfma_f32_16x16x32_bf16(
                    af[tm], bf[tn], acc2[tm][tn], 0, 0, 0);
    }

    #pragma unroll
    for (int tm = 0; tm < 2; ++tm)
        #pragma unroll
        for (int tn = 0; tn < 8; ++tn) {
            const int col = tn*16 + l16;
            #pragma unroll
            for (int rg = 0; rg < 4; ++rg) {
                const int m = mbase + tm*16 + q*4 + rg;
                const int pix = pixbase + m;
                size_t off = ((size_t)n_img * 1024 + pix) * 128 + col;
                float v = acc2[tm][tn][rg] + bf2f(in[off]);
                if (FRELU) v = fmaxf(v, 0.0f);
                out[off] = f2bf(v);
            }
        }
}

// ---------------- fused enc_adj (1x1 128->64) + VQ ----------------
__global__ __launch_bounds__(256)
void adjvq_k(const u16* __restrict__ TRin, const u16* __restrict__ wadj,
             const float* __restrict__ bias, const u16* __restrict__ Ebf,
             const float* __restrict__ enorm1, u16* __restrict__ Zq,
             u16* __restrict__ idx_out, float* __restrict__ sse)
{
    constexpr int LDA = 40;
    __shared__ alignas(16) u16 smem[18432];   // 36.9KB aliased region
    u16* aT  = smem;             // [0,5120)   phase A
    u16* bT  = smem + 5120;      // [5120,7680)
    u16* mT0 = smem;             // [0,5120)   Ze k0..31
    u16* mT1 = smem + 5120;      // [5120,10240) Ze k32..63
    u16* eld = smem;             // [0,18432)  codebook pass
    __shared__ float znorm_s[128];
    __shared__ float bestf_s[128];
    __shared__ float en1s[256];
    __shared__ int   bestk_s[128];
    __shared__ float red[256];

    const int tid = threadIdx.x;
    const int r = tid >> 1, half = tid & 1;
    const int bx = swz512(blockIdx.x);
    const size_t gp = (size_t)bx * 128 + r;
    const u16* arow = TRin + gp * 128 + half * 16;
    const u16* brow = wadj + (size_t)r * 128 + half * 16;

    const int wv = tid >> 6, lane = tid & 63;
    const int q = lane >> 4, l16 = lane & 15;
    const int mbase = wv * 32;

    // ---- phase A: 1x1 conv (input already relu'd) ----
    f32x4 acc[2][4] = {};
    for (int c0 = 0; c0 < 128; c0 += 32) {
        __syncthreads();
        uint4 a0 = *(const uint4*)(arow + c0);
        uint4 a1 = *(const uint4*)(arow + c0 + 8);
        *(uint4*)&aT[r * LDA + half * 16]     = a0;
        *(uint4*)&aT[r * LDA + half * 16 + 8] = a1;
        if (r < 64) {
            *(uint4*)&bT[r * LDA + half * 16]     = *(const uint4*)(brow + c0);
            *(uint4*)&bT[r * LDA + half * 16 + 8] = *(const uint4*)(brow + c0 + 8);
        }
        __syncthreads();
        bf16x8 afr[2], bfr[4];
        #pragma unroll
        for (int tm = 0; tm < 2; ++tm)
            afr[tm] = *(const bf16x8*)&aT[(mbase + tm*16 + l16) * LDA + q * 8];
        #pragma unroll
        for (int tn = 0; tn < 4; ++tn)
            bfr[tn] = *(const bf16x8*)&bT[(tn*16 + l16) * LDA + q * 8];
        #pragma unroll
        for (int tm = 0; tm < 2; ++tm)
            #pragma unroll
            for (int tn = 0; tn < 4; ++tn)
                acc[tm][tn] = __builtin_amdgcn_mfma_f32_16x16x32_bf16(
                    afr[tm], bfr[tn], acc[tm][tn], 0, 0, 0);
    }

    // bias + znorm (fp32) per row
    float zn[2][4] = {};   // [tm][rg]
    #pragma unroll
    for (int tm = 0; tm < 2; ++tm)
        #pragma unroll
        for (int tn = 0; tn < 4; ++tn) {
            const float bv = bias[tn*16 + l16];
            #pragma unroll
            for (int rg = 0; rg < 4; ++rg) {
                float z = acc[tm][tn][rg] + bv;
                acc[tm][tn][rg] = z;
                zn[tm][rg] = fmaf(z, z, zn[tm][rg]);
            }
        }
    #pragma unroll
    for (int m = 1; m < 16; m <<= 1)
        #pragma unroll
        for (int tm = 0; tm < 2; ++tm)
            #pragma unroll
            for (int rg = 0; rg < 4; ++rg)
                zn[tm][rg] += __shfl_xor(zn[tm][rg], m, 64);

    __syncthreads();   // all phase-A LDS reads done before mT overwrite

    #pragma unroll
    for (int tm = 0; tm < 2; ++tm) {
        #pragma unroll
        for (int tn = 0; tn < 4; ++tn) {
            u16* dst = (tn < 2) ? mT0 : mT1;
            const int kc = (tn & 1) * 16 + l16;
            #pragma unroll
            for (int rg = 0; rg < 4; ++rg) {
                int row = mbase + tm*16 + q*4 + rg;
                dst[row * LDA + kc] = f2bf(acc[tm][tn][rg]);
            }
        }
        if (l16 == 0)
            #pragma unroll
            for (int rg = 0; rg < 4; ++rg)
                znorm_s[mbase + tm*16 + q*4 + rg] = zn[tm][rg];
    }
    __syncthreads();

    // Ze A-fragments (rows mbase..mbase+31)
    bf16x8 alo[2], ahi[2];
    #pragma unroll
    for (int tile = 0; tile < 2; ++tile) {
        alo[tile] = *(const bf16x8*)&mT0[(mbase + tile*16 + l16) * LDA + q * 8];
        ahi[tile] = *(const bf16x8*)&mT1[(mbase + tile*16 + l16) * LDA + q * 8];
    }

    // ---- VQ ----
    unsigned key[2][4] = {{0xFFFFFFFFu,0xFFFFFFFFu,0xFFFFFFFFu,0xFFFFFFFFu},
                          {0xFFFFFFFFu,0xFFFFFFFFu,0xFFFFFFFFu,0xFFFFFFFFu}};
    float fb[2][4] = {{1e30f,1e30f,1e30f,1e30f},{1e30f,1e30f,1e30f,1e30f}};

    for (int k0 = 0; k0 < 512; k0 += 256) {
        __syncthreads();
        const uint4* src = (const uint4*)(Ebf + k0 * 64);
        #pragma unroll
        for (int i = tid; i < 2048; i += 256) {
            int row = i >> 3, sub = i & 7;
            *(uint4*)&eld[row * 72 + sub * 8] = src[i];
        }
        en1s[tid] = enorm1[k0 + tid];
        __syncthreads();

        for (int t = 0; t < 16; ++t) {
            const int nl = t * 16 + l16;
            bf16x8 b0 = *(const bf16x8*)&eld[nl * 72 + q * 8];
            bf16x8 b1 = *(const bf16x8*)&eld[nl * 72 + 32 + q * 8];
            const float en1 = en1s[nl];
            const unsigned ng = (unsigned)(k0 + nl);
            #pragma unroll
            for (int tile = 0; tile < 2; ++tile) {
                f32x4 sc4 = {0.0f, 0.0f, 0.0f, 0.0f};
                sc4 = __builtin_amdgcn_mfma_f32_16x16x32_bf16(alo[tile], b0, sc4, 0, 0, 0);
                sc4 = __builtin_amdgcn_mfma_f32_16x16x32_bf16(ahi[tile], b1, sc4, 0, 0, 0);
                #pragma unroll
                for (int rg = 0; rg < 4; ++rg) {
                    float sc = fmaf(sc4[rg], -2.0f, en1);
                    unsigned kk2 = (__float_as_uint(sc) & 0xFFFFFE00u) | ng;
                    key[tile][rg] = min(key[tile][rg], kk2);
                    fb[tile][rg] = fminf(fb[tile][rg], sc);
                }
            }
        }
    }

    #pragma unroll
    for (int m = 1; m < 16; m <<= 1)
        #pragma unroll
        for (int tile = 0; tile < 2; ++tile)
            #pragma unroll
            for (int rg = 0; rg < 4; ++rg) {
                unsigned o = (unsigned)__shfl_xor((int)key[tile][rg], m, 64);
                key[tile][rg] = min(key[tile][rg], o);
                float of = __shfl_xor(fb[tile][rg], m, 64);
                fb[tile][rg] = fminf(fb[tile][rg], of);
            }
    if (l16 == 0)
        #pragma unroll
        for (int tile = 0; tile < 2; ++tile)
            #pragma unroll
            for (int rg = 0; rg < 4; ++rg) {
                int row = mbase + tile*16 + q*4 + rg;
                bestk_s[row] = (int)(key[tile][rg] & 511u);
                bestf_s[row] = fb[tile][rg];
            }
    __syncthreads();

    // epilogue: Zq copy + idx + SSE
    const int pos = tid >> 1, seg = tid & 1;
    const size_t p = (size_t)bx * 128 + pos;
    const int k = bestk_s[pos];
    const u16* ep = Ebf + (size_t)k * 64 + seg * 32;
    u16* qp = Zq + p * 64 + seg * 32;
    #pragma unroll
    for (int h = 0; h < 4; ++h)
        *(uint4*)(qp + h * 8) = *(const uint4*)(ep + h * 8);
    if (seg == 0) idx_out[p] = (u16)k;
    red[tid] = (seg == 0) ? (znorm_s[pos] + bestf_s[pos] - 1.0f) : 0.0f;
    __syncthreads();
    for (int s = 128; s > 0; s >>= 1) {
        if (tid < s) red[tid] += red[tid + s];
        __syncthreads();
    }
    if (tid == 0) atomicAdd(sse, red[0]);
}

// ---------------- conv1 as MFMA im2col GEMM ----------------
__global__ __launch_bounds__(256)
void conv1_mfma_k(const float* __restrict__ x, const u16* __restrict__ wc1b,
                  const float* __restrict__ b, u16* __restrict__ out)
{
    __shared__ alignas(16) u16 smem[15360];
    u16* aT0 = smem;
    u16* aT1 = smem + 5120;
    u16* bT0 = smem + 10240;
    u16* bT1 = smem + 12800;

    const int tid = threadIdx.x;
    const int gbase = blockIdx.x * 128;
    const int r = tid >> 1, half = tid & 1;
    const int p = gbase + r;
    const int ow = p & 63, oh = (p >> 6) & 63, n = p >> 12;
    const float* xb = x + (size_t)n * 3 * 16384;

    {
        int row = tid >> 2, sub = tid & 3;
        *(uint4*)&bT0[row*40 + sub*8] = *(const uint4*)(wc1b + row*64 + sub*8);
        *(uint4*)&bT1[row*40 + sub*8] = *(const uint4*)(wc1b + row*64 + 32 + sub*8);
    }

    float vals[24];
    const int kb = half * 24;
    #pragma unroll
    for (int j = 0; j < 24; ++j) {
        int k = kb + j;
        int ci = k >> 4, kh = (k >> 2) & 3, kw = k & 3;
        int ih = oh*2 - 1 + kh, iw = ow*2 - 1 + kw;
        bool ok = ((unsigned)ih < 128u) && ((unsigned)iw < 128u);
        vals[j] = ok ? xb[ci*16384 + ih*128 + iw] : 0.0f;
    }
    unsigned pk[12];
    #pragma unroll
    for (int jj = 0; jj < 12; ++jj)
        pk[jj] = (unsigned)f2bf(vals[2*jj]) | ((unsigned)f2bf(vals[2*jj+1]) << 16);
    unsigned* a0row = (unsigned*)&aT0[r * 40];
    unsigned* a1row = (unsigned*)&aT1[r * 40];
    if (half == 0) {
        #pragma unroll
        for (int jj = 0; jj < 12; ++jj) a0row[jj] = pk[jj];
    } else {
        a0row[12] = pk[0]; a0row[13] = pk[1];
        a0row[14] = pk[2]; a0row[15] = pk[3];
        #pragma unroll
        for (int jj = 4; jj < 12; ++jj) a1row[jj - 4] = pk[jj];
        *(uint4*)&aT1[r*40 + 16] = (uint4){0,0,0,0};
        *(uint4*)&aT1[r*40 + 24] = (uint4){0,0,0,0};
    }
    __syncthreads();

    const int wv = tid >> 6, lane = tid & 63;
    const int q = lane >> 4, l16 = lane & 15;
    const int mbase = wv * 32;

    f32x4 acc[2][4] = {};
    bf16x8 af0[2], af1[2], bf0[4], bf1[4];
    #pragma unroll
    for (int tm = 0; tm < 2; ++tm) {
        af0[tm] = *(const bf16x8*)&aT0[(mbase + tm*16 + l16) * 40 + q * 8];
        af1[tm] = *(const bf16x8*)&aT1[(mbase + tm*16 + l16) * 40 + q * 8];
    }
    #pragma unroll
    for (int tn = 0; tn < 4; ++tn) {
        bf0[tn] = *(const bf16x8*)&bT0[(tn*16 + l16) * 40 + q * 8];
        bf1[tn] = *(const bf16x8*)&bT1[(tn*16 + l16) * 40 + q * 8];
    }
    #pragma unroll
    for (int tm = 0; tm < 2; ++tm)
        #pragma unroll
        for (int tn = 0; tn < 4; ++tn) {
            acc[tm][tn] = __builtin_amdgcn_mfma_f32_16x16x32_bf16(
                af0[tm], bf0[tn], acc[tm][tn], 0, 0, 0);
            acc[tm][tn] = __builtin_amdgcn_mfma_f32_16x16x32_bf16(
                af1[tm], bf1[tn], acc[tm][tn], 0, 0, 0);
        }

    float bv[4];
    #pragma unroll
    for (int tn = 0; tn < 4; ++tn) bv[tn] = b[tn*16 + l16];

    __syncthreads();
    u16* cbuf = smem;
    #pragma unroll
    for (int tm = 0; tm < 2; ++tm)
        #pragma unroll
        for (int tn = 0; tn < 4; ++tn)
            #pragma unroll
            for (int rg = 0; rg < 4; ++rg) {
                int row = mbase + tm*16 + q*4 + rg;
                int col = tn*16 + l16;
                cbuf[row*72 + col] = f2bf(fmaxf(acc[tm][tn][rg] + bv[tn], 0.0f));
            }
    __syncthreads();

    u16* ob = out + (size_t)gbase * 64;
    #pragma unroll
    for (int it = 0; it < 4; ++it) {
        int j = it * 256 + tid;
        uint4 v = *(const uint4*)&cbuf[(j >> 3) * 72 + (j & 7) * 8];
        *(uint4*)(ob + j * 8) = v;
    }
}

// ---------------- tc2 as MFMA parity GEMM ----------------
__global__ __launch_bounds__(256)
void tc2_mfma_k(const u16* __restrict__ in, const u16* __restrict__ wT,
                const float* __restrict__ bias, float* __restrict__ out)
{
    constexpr int LDA = 40;
    __shared__ alignas(16) u16 aT[128 * LDA];
    __shared__ alignas(16) u16 bT[16 * LDA];
    __shared__ float cT[128 * 17];

    const int tid = threadIdx.x;
    const int m0 = blockIdx.x * 128;
    const int n_img = m0 >> 12;
    const int pixbase = m0 & 4095;
    const int y0 = pixbase >> 6;

    const int r = tid >> 1, half = tid & 1;
    const int pr = pixbase + r;
    const int yr = pr >> 6, xr = pr & 63;
    const u16* inb = in + (size_t)n_img * 4096 * 64;

    const int wv = tid >> 6, lane = tid & 63;
    const int q = lane >> 4, l16 = lane & 15;
    const int mbase = wv * 32;

    f32x4 acc[2] = {};

    for (int t = 0; t < 9; ++t) {
        const int ih = yr + t/3 - 1;
        const int iw = xr + t%3 - 1;
        const bool ok = ((unsigned)ih < 64u) && ((unsigned)iw < 64u);
        const u16* asrc = ok ? (inb + ((size_t)ih * 64 + iw) * 64 + half * 16) : inb;
        const u16* bsrc = wT + ((size_t)t * 16 + r) * 64 + half * 16;

        for (int c0 = 0; c0 < 64; c0 += 32) {
            __syncthreads();
            uint4 a0 = {0,0,0,0}, a1 = {0,0,0,0};
            if (ok) {
                a0 = *(const uint4*)(asrc + c0);
                a1 = *(const uint4*)(asrc + c0 + 8);
            }
            *(uint4*)&aT[r * LDA + half * 16]     = a0;
            *(uint4*)&aT[r * LDA + half * 16 + 8] = a1;
            if (r < 16) {
                *(uint4*)&bT[r * LDA + half * 16]     = *(const uint4*)(bsrc + c0);
                *(uint4*)&bT[r * LDA + half * 16 + 8] = *(const uint4*)(bsrc + c0 + 8);
            }
            __syncthreads();

            bf16x8 af0 = *(const bf16x8*)&aT[(mbase + l16) * LDA + q * 8];
            bf16x8 af1 = *(const bf16x8*)&aT[(mbase + 16 + l16) * LDA + q * 8];
            bf16x8 bf  = *(const bf16x8*)&bT[l16 * LDA + q * 8];
            acc[0] = __builtin_amdgcn_mfma_f32_16x16x32_bf16(af0, bf, acc[0], 0, 0, 0);
            acc[1] = __builtin_amdgcn_mfma_f32_16x16x32_bf16(af1, bf, acc[1], 0, 0, 0);
        }
    }

    #pragma unroll
    for (int tm = 0; tm < 2; ++tm)
        #pragma unroll
        for (int rg = 0; rg < 4; ++rg)
            cT[(mbase + tm*16 + q*4 + rg) * 17 + l16] = acc[tm][rg];
    __syncthreads();

    #pragma unroll
    for (int it = 0; it < 6; ++it) {
        int j = it * 256 + tid;
        int co  = j >> 9;
        int rem = j & 511;
        int ohl = rem >> 7;
        int ow  = rem & 127;
        int oh  = 2*y0 + ohl;
        int lp  = (ohl >> 1) * 64 + (ow >> 1);
        int col = ((ohl & 1) * 2 + (ow & 1)) * 4 + co;
        float v = cT[lp * 17 + col] + bias[co];
        out[(((size_t)n_img * 3 + co) * 128 + oh) * 128 + ow] = v;
    }
}

// ---------------- histogram by scan ----------------
__global__ __launch_bounds__(256)
void hist_k(const u16* __restrict__ idx, float* __restrict__ counts)
{
    __shared__ int red[256];
    const int k = blockIdx.x;
    const int tid = threadIdx.x;
    int c = 0;
    const uint4* p4 = (const uint4*)idx;
    for (int i = tid; i < 8192; i += 256) {
        uint4 v = p4[i];
        unsigned ua[4] = {v.x, v.y, v.z, v.w};
        #pragma unroll
        for (int j = 0; j < 4; ++j) {
            c += ((ua[j] & 0xFFFFu) == (unsigned)k);
            c += ((ua[j] >> 16)     == (unsigned)k);
        }
    }
    red[tid] = c;
    __syncthreads();
    for (int s = 128; s > 0; s >>= 1) {
        if (tid < s) red[tid] += red[tid + s];
        __syncthreads();
    }
    if (tid == 0) counts[k] = (float)red[0];
}

// ---------------- merged prep ----------------
__device__ __forceinline__ void wconv_tf(const float* __restrict__ w,
                                         u16* __restrict__ o,
                                         int COUT, int CIN, int KK, int i)
{
    int ci = i % CIN; int t = i / CIN; int co = t % COUT; t /= COUT;
    o[i] = f2bf(w[(co*CIN + ci)*KK + t]);
}

__global__ __launch_bounds__(256)
void prep_k(const float* __restrict__ enc_w1, const float* __restrict__ enc_w2,
            const float* __restrict__ enc_w3, const float* __restrict__ enc_w4,
            const float* __restrict__ enc_res_w1, const float* __restrict__ enc_res_w2,
            const float* __restrict__ dec_res_w1, const float* __restrict__ dec_res_w2,
            const float* __restrict__ enc_adj_w, const float* __restrict__ dec_adj_w,
            const float* __restrict__ tc1_w, const float* __restrict__ tc2_w,
            const float* __restrict__ E,
            u16* __restrict__ wc1b, u16* __restrict__ wc2, u16* __restrict__ wc3,
            u16* __restrict__ wc4, u16* __restrict__ wer1, u16* __restrict__ wer2,
            u16* __restrict__ wdr1, u16* __restrict__ wdr2, u16* __restrict__ weadj,
            u16* __restrict__ wdadj, u16* __restrict__ wtc1, u16* __restrict__ wtc2b,
            u16* __restrict__ Ebf, float* __restrict__ enorm1, float* __restrict__ sse)
{
    const int b = blockIdx.x, tid = threadIdx.x;
    if (b < 512) {
        wconv_tf(enc_w2, wc2, 128, 64, 16, b * 256 + tid);
    } else if (b < 1088) {
        wconv_tf(enc_w3, wc3, 128, 128, 9, (b - 512) * 256 + tid);
    } else if (b < 1664) {
        wconv_tf(enc_w4, wc4, 128, 128, 9, (b - 1088) * 256 + tid);
    } else if (b < 2240) {
        int i = (b - 1664) * 256 + tid;
        int sub = i / 73728, rem = i - sub * 73728;
        wconv_tf(enc_res_w1 + sub * 73728, wer1 + sub * 73728, 64, 128, 9, rem);
    } else if (b < 2816) {
        int i = (b - 2240) * 256 + tid;
        int sub = i / 73728, rem = i - sub * 73728;
        wconv_tf(dec_res_w1 + sub * 73728, wdr1 + sub * 73728, 64, 128, 9, rem);
    } else if (b < 2880) {
        int i = (b - 2816) * 256 + tid;
        int sub = i >> 13, rem = i & 8191;
        wconv_tf(enc_res_w2 + sub * 8192, wer2 + sub * 8192, 128, 64, 1, rem);
    } else if (b < 2944) {
        int i = (b - 2880) * 256 + tid;
        int sub = i >> 13, rem = i & 8191;
        wconv_tf(dec_res_w2 + sub * 8192, wdr2 + sub * 8192, 128, 64, 1, rem);
    } else if (b < 2976) {
        wconv_tf(enc_adj_w, weadj, 64, 128, 1, (b - 2944) * 256 + tid);
    } else if (b < 3264) {
        wconv_tf(dec_adj_w, wdadj, 128, 64, 9, (b - 2976) * 256 + tid);
    } else if (b < 3776) {
        int i = (b - 3264) * 256 + tid;
        int ci = i & 127; int co = (i >> 7) & 63; int t = (i >> 13) & 3; int p = i >> 15;
        int poh = p >> 1, pw = p & 1; int a = t >> 1, bb = t & 1;
        int kh = poh ? (a ? 2 : 0) : (a ? 3 : 1);
        int kw = pw  ? (bb ? 2 : 0) : (bb ? 3 : 1);
        wtc1[i] = f2bf(tc1_w[((ci*64 + co)*4 + kh)*4 + kw]);
    } else if (b < 3812) {
        int i = (b - 3776) * 256 + tid;
        int ci = i & 63; int col = (i >> 6) & 15; int t = i >> 10;
        int dh = t / 3 - 1, dw = t % 3 - 1;
        int pp = col >> 2, co = col & 3;
        float v = 0.0f;
        if (co < 3) {
            int poh = pp >> 1, pw = pp & 1;
            int kh = poh ? (dh == 1 ? 0 : (dh == 0 ? 2 : -1))
                         : (dh == 0 ? 1 : (dh == -1 ? 3 : -1));
            int kw = pw  ? (dw == 1 ? 0 : (dw == 0 ? 2 : -1))
                         : (dw == 0 ? 1 : (dw == -1 ? 3 : -1));
            if (kh >= 0 && kw >= 0)
                v = tc2_w[((ci*3 + co)*4 + kh)*4 + kw];
        }
        wtc2b[i] = f2bf(v);
    } else if (b < 3814) {
        int k = (b - 3812) * 256 + tid;
        float s = 0.0f;
        #pragma unroll
        for (int d = 0; d < 64; ++d) {
            u16 h = f2bf(E[k*64 + d]);
            Ebf[k*64 + d] = h;
            float v = bf2f(h);
            s = fmaf(v, v, s);
        }
        enorm1[k] = s + 1.0f;
    } else if (b < 3830) {
        int i = (b - 3814) * 256 + tid;
        int co = i >> 6, k = i & 63;
        float v = 0.0f;
        if (k < 48) {
            int ci = k >> 4, kh = (k >> 2) & 3, kw = k & 3;
            v = enc_w1[((co*3 + ci)*4 + kh)*4 + kw];
        }
        wc1b[i] = f2bf(v);
    } else {
        if (tid == 0) sse[0] = 0.0f;
    }
}

// ---------------- scalars ----------------
__global__ void finalize_k(const float* __restrict__ counts, const float* __restrict__ sse,
                           float* __restrict__ out_head, float* __restrict__ out_tail)
{
    __shared__ float red[512];
    int t = threadIdx.x;
    float pr = counts[t] / 65536.0f;
    red[t] = -pr * log2f(pr + 1e-10f);
    __syncthreads();
    for (int s = 256; s > 0; s >>= 1) {
        if (t < s) red[t] += red[t + s];
        __syncthreads();
    }
    if (t == 0) {
        float entropy = red[0];
        float mse = sse[0] / 4194304.0f;
        out_head[0] = 1.25f * mse;
        out_tail[0] = mse;
        out_tail[1] = mse;
        out_tail[2] = exp2f(entropy);
    }
}

// ---------------------------------------------------------------------------
extern "C" void kernel_launch(void* const* d_in, const int* in_sizes, int n_in,
                              void* d_out, int out_size, void* d_ws, size_t ws_size,
                              hipStream_t stream)
{
    const float* x         = (const float*)d_in[0];
    const float* enc_w1    = (const float*)d_in[1];
    const float* enc_b1    = (const float*)d_in[2];
    const float* enc_w2    = (const float*)d_in[3];
    const float* enc_b2    = (const float*)d_in[4];
    const float* enc_w3    = (const float*)d_in[5];
    const float* enc_b3    = (const float*)d_in[6];
    const float* enc_w4    = (const float*)d_in[7];
    const float* enc_b4    = (const float*)d_in[8];
    const float* enc_res_w1= (const float*)d_in[9];
    const float* enc_res_w2= (const float*)d_in[10];
    const float* enc_adj_w = (const float*)d_in[11];
    const float* enc_adj_b = (const float*)d_in[12];
    const float* Ecb       = (const float*)d_in[13];
    const float* dec_adj_w = (const float*)d_in[14];
    const float* dec_adj_b = (const float*)d_in[15];
    const float* dec_res_w1= (const float*)d_in[16];
    const float* dec_res_w2= (const float*)d_in[17];
    const float* tc1_w     = (const float*)d_in[18];
    const float* tc1_b     = (const float*)d_in[19];
    const float* tc2_w     = (const float*)d_in[20];
    const float* tc2_b     = (const float*)d_in[21];

    char* wsb = (char*)d_ws;
    u16*   wc2   = (u16*)(wsb + 0);
    u16*   wc3   = (u16*)(wsb + 262144);
    u16*   wc4   = (u16*)(wsb + 557056);
    u16*   wer1  = (u16*)(wsb + 851968);
    u16*   wer2  = (u16*)(wsb + 1146880);
    u16*   weadj = (u16*)(wsb + 1179648);
    u16*   wdadj = (u16*)(wsb + 1196032);
    u16*   wdr1  = (u16*)(wsb + 1343488);
    u16*   wdr2  = (u16*)(wsb + 1638400);
    u16*   wtc1  = (u16*)(wsb + 1671168);
    u16*   wtc2b = (u16*)(wsb + 1933312);
    float* counts= (float*)(wsb + 1951744);
    float* sse   = counts + 512;
    u16*   Ebf   = (u16*)(wsb + 1955840);
    float* enorm1= (float*)(wsb + 2021376);
    u16*   wc1b  = (u16*)(wsb + 2023424);
    u16*   H1    = (u16*)(wsb + 2097152);
    u16*   TR    = (u16*)(wsb + 35651584);
    u16*   H3    = (u16*)(wsb + 52428800);
    u16*   ZQ    = (u16*)(wsb + 85983232);
    u16*   IDX   = (u16*)(wsb + 94371840);
    u16*   TC1O  = H1;

    float* out  = (float*)d_out;
    float* xrec = out + 1;
    float* tail = out + 1 + 3145728;

    // ---- single merged prep dispatch ----
    prep_k<<<3831, 256, 0, stream>>>(enc_w1, enc_w2, enc_w3, enc_w4,
        enc_res_w1, enc_res_w2, dec_res_w1, dec_res_w2, enc_adj_w, dec_adj_w,
        tc1_w, tc2_w, Ecb, wc1b, wc2, wc3, wc4, wer1, wer2, wdr1, wdr2,
        weadj, wdadj, wtc1, wtc2b, Ebf, enorm1, sse);

    // ---- encoder ----
    conv1_mfma_k<<<2048, 256, 0, stream>>>(x, wc1b, enc_b1, H1);
    mfma_conv512_k<64,2,true ><<<512, 512, 0, stream>>>
        (H1, wc2, enc_b2, TR, 64, 64, 32, 32);
    mfma_conv512_k<128,1,true ><<<512, 512, 0, stream>>>
        (TR, wc3, enc_b3, H3, 32, 32, 32, 32);
    mfma_conv512_k<128,1,false><<<512, 512, 0, stream>>>
        (H3, wc4, enc_b4, TR, 32, 32, 32, 32);
    // fused res blocks: TR -> H3 -> TR (2nd block writes post-relu for adjvq)
    res_fused_k<false><<<512, 256, 0, stream>>>(TR, wer1,         wer2,        H3);
    res_fused_k<true ><<<512, 256, 0, stream>>>(H3, wer1 + 73728, wer2 + 8192, TR);

    // ---- fused enc_adj + VQ ----
    adjvq_k<<<512, 256, 0, stream>>>(TR, weadj, enc_adj_b, Ebf, enorm1,
                                     ZQ, IDX, sse);
    hist_k<<<512, 256, 0, stream>>>(IDX, counts);

    // ---- decoder ----
    mfma_conv512_k<64,1,false><<<512, 512, 0, stream>>>
        (ZQ, wdadj, dec_adj_b, H3, 32, 32, 32, 32);
    // fused res blocks: H3 -> TR -> H3 (2nd block writes post-relu for tc1)
    res_fused_k<false><<<512, 256, 0, stream>>>(H3, wdr1,         wdr2,        TR);
    res_fused_k<true ><<<512, 256, 0, stream>>>(TR, wdr1 + 73728, wdr2 + 8192, H3);
    // tc1: all 4 parities in one dispatch (blockIdx.z); input pre-relu'd
    mfma_conv_k<128,64,3,false,true,true,false><<<dim3(512,1,4), 256, 0, stream>>>
        (H3, wtc1, tc1_b, TC1O, 32, 32, 64, 64, 2);
    tc2_mfma_k<<<2048, 256, 0, stream>>>(TC1O, wtc2b, tc2_b, xrec);

    // ---- scalars ----
    finalize_k<<<1, 512, 0, stream>>>(counts, sse, out, tail);
}